// Round 13
// baseline (189.343 us; speedup 1.0000x reference)
//
#include <hip/hip_runtime.h>
#include <math.h>

#define NB 2
#define NH 16
#define NT 2048
#define ND 64
#define NC 1024
#define L2E 1.44269504f

typedef __attribute__((ext_vector_type(4))) float f32x4;
typedef __attribute__((ext_vector_type(8))) short short8;
typedef __attribute__((ext_vector_type(4))) short short4_t;
typedef __attribute__((ext_vector_type(8))) unsigned short ushort8;
typedef __attribute__((ext_vector_type(4))) unsigned short ushort4_t;

#define GLOAD_LDS(gp, lp)                                                \
    __builtin_amdgcn_global_load_lds(                                    \
        (const __attribute__((address_space(1))) void*)(gp),             \
        (__attribute__((address_space(3))) void*)(lp), 16, 0, 0)

// storage permutation: position p holds logical index
// sigma(p) = 4*((p>>3)&3) + (p&3) + 16*((p>>2)&1) + 32*(p>>5)
// fragment (g,h) = one contiguous 16B at ushort offset 8g+32h.
__device__ __forceinline__ int sigma_p(int p) {
    return 4 * ((p >> 3) & 3) + (p & 3) + 16 * ((p >> 2) & 1) + 32 * (p >> 5);
}

__device__ __forceinline__ unsigned short f2bf(float f) {
    unsigned u = __builtin_bit_cast(unsigned, f);
    unsigned r = (u + 0x7FFFu + ((u >> 16) & 1u)) >> 16;
    return (unsigned short)r;
}

__device__ __forceinline__ unsigned cvtpk_bf16(float lo, float hi) {
    unsigned r;
    asm("v_cvt_pk_bf16_f32 %0, %1, %2" : "=v"(r) : "v"(lo), "v"(hi));
    return r;
}

__device__ __forceinline__ f32x4 mfma16(short8 a, short8 b, f32x4 c) {
    return __builtin_amdgcn_mfma_f32_16x16x32_bf16(a, b, c, 0, 0, 0);
}

// split-fragment load (out_proj path, logical order)
__device__ __forceinline__ short8 frag_load(const unsigned short* rowp, int g, int half) {
    short8 v;
    short4_t lo = *(const short4_t*)(rowp + 4 * g + 32 * half);
    short4_t hi = *(const short4_t*)(rowp + 4 * g + 16 + 32 * half);
    #pragma unroll
    for (int j = 0; j < 4; ++j) { v[j] = lo[j]; v[4 + j] = hi[j]; }
    return v;
}

// sigma-stored global row: fragment = single 16B load
__device__ __forceinline__ short8 frag_g(const unsigned short* rowp, int g, int half) {
    return *(const short8*)(rowp + 8 * g + 32 * half);
}

// sigma-stored LDS tile with per-row chunk XOR swizzle: one ds_read_b128
__device__ __forceinline__ short8 frag_swz128(const unsigned short* tile, int row, int g, int half) {
    const char* p = (const char*)tile + row * 128 + (((g + 4 * half) ^ (row & 7)) << 4);
    return *(const short8*)p;
}

// ---------------------------------------------------------------------------
// x f32 -> bf16 with sigma permutation of each 64-dim block
// ---------------------------------------------------------------------------
__global__ __launch_bounds__(256) void cvt_x(const float* __restrict__ src,
                                             unsigned short* __restrict__ dst, int n4) {
    int i = blockIdx.x * 256 + threadIdx.x;
    if (i >= n4) return;
    const int blk = i >> 4, c4 = i & 15;
    const int gg = (c4 >> 1) & 3, bb = c4 & 1, hh = c4 >> 3;
    f32x4 v = ((const f32x4*)src)[blk * 16 + gg + 4 * bb + 8 * hh];
    ushort4_t o;
    #pragma unroll
    for (int j = 0; j < 4; ++j) o[j] = f2bf(v[j]);
    ((ushort4_t*)dst)[i] = o;
}

// ---------------------------------------------------------------------------
// three weight matrices f32 [k][n] -> bf16 [n][k-sigma], one launch
// ---------------------------------------------------------------------------
__global__ __launch_bounds__(256) void cvtT3(const float* __restrict__ w0,
                                             const float* __restrict__ w1,
                                             const float* __restrict__ w2,
                                             unsigned short* __restrict__ Wt_all) {
    __shared__ __align__(16) float T[64][68];
    const float* W = (blockIdx.z == 0) ? w0 : ((blockIdx.z == 1) ? w1 : w2);
    unsigned short* Wt = Wt_all + (size_t)blockIdx.z * NC * NC;
    const int tid = threadIdx.x;
    const int k0 = blockIdx.x * 64, n0 = blockIdx.y * 64;
    #pragma unroll
    for (int p = 0; p < 4; ++p) {
        int r = 16 * p + (tid >> 4);
        int c = (tid & 15) * 4;
        *(f32x4*)&T[r][c] = *(const f32x4*)&W[(size_t)(k0 + r) * NC + n0 + c];
    }
    __syncthreads();
    const int nr = tid >> 2, kc = (tid & 3) * 16;
    ushort8 o0, o1;
    #pragma unroll
    for (int j = 0; j < 8; ++j) o0[j] = f2bf(T[sigma_p(kc + j)][nr]);
    #pragma unroll
    for (int j = 0; j < 8; ++j) o1[j] = f2bf(T[sigma_p(kc + 8 + j)][nr]);
    unsigned short* q = Wt + (size_t)(n0 + nr) * NC + k0 + kc;
    *(ushort8*)q       = o0;
    *(ushort8*)(q + 8) = o1;
}

// ---------------------------------------------------------------------------
// wo f32 [k=64][n=1024] -> bf16 [n][k] (logical order)
// ---------------------------------------------------------------------------
__global__ __launch_bounds__(256) void cvtT_wo(const float* __restrict__ W,
                                               unsigned short* __restrict__ Wt) {
    __shared__ __align__(16) float T[64][68];
    const int tid = threadIdx.x;
    const int n0 = blockIdx.y * 64;
    #pragma unroll
    for (int p = 0; p < 4; ++p) {
        int r = 16 * p + (tid >> 4);
        int c = (tid & 15) * 4;
        *(f32x4*)&T[r][c] = *(const f32x4*)&W[(size_t)r * NC + n0 + c];
    }
    __syncthreads();
    const int nr = tid >> 2, kc = (tid & 3) * 16;
    ushort8 o0, o1;
    #pragma unroll
    for (int j = 0; j < 8; ++j) { o0[j] = f2bf(T[kc + j][nr]); o1[j] = f2bf(T[kc + 8 + j][nr]); }
    unsigned short* q = Wt + (size_t)(n0 + nr) * ND + kc;
    *(ushort8*)q       = o0;
    *(ushort8*)(q + 8) = o1;
}

// ---------------------------------------------------------------------------
// bf16 MFMA GEMM, 128x128 tile, 4 waves, K-step 64, single launch for Q,K,V.
// Q/K -> sigma-d [bh][t][d']; V -> DIRECT transposed write Vt[bh][d][t-sigma].
// ---------------------------------------------------------------------------
__global__ __launch_bounds__(256) void gemm_qkv(const unsigned short* __restrict__ Xh,
                                                const unsigned short* __restrict__ Wt_all,
                                                unsigned short* __restrict__ qk_dst,
                                                unsigned short* __restrict__ Vt) {
    __shared__ __align__(16) unsigned short Xs[2][8192];
    __shared__ __align__(16) unsigned short Ws[2][8192];
    const int tid = threadIdx.x;
    const int lane = tid & 63, w = tid >> 6;
    const int g = lane >> 4, l15 = lane & 15;
    const int wr = w >> 1, wc = w & 1;
    const int subrow = lane >> 3;
    const int src_off = (((lane & 7) ^ subrow) << 4);
    const int m0 = blockIdx.x * 128;
    const int which = blockIdx.y >> 3;
    const int n0 = (blockIdx.y & 7) * 128;
    const unsigned short* Wt = Wt_all + (size_t)which * NC * NC;

    f32x4 acc[4][4] = {};

    auto stage = [&](int buf, int kk) {
        #pragma unroll
        for (int i = 0; i < 4; ++i) {
            const int r0 = 8 * w + 32 * i;
            const char* xs = (const char*)Xh + (((size_t)(m0 + r0 + subrow) * NC + kk) << 1) + src_off;
            GLOAD_LDS(xs, (char*)&Xs[buf][r0 * 64]);
            const char* ws = (const char*)Wt + (((size_t)(n0 + r0 + subrow) * NC + kk) << 1) + src_off;
            GLOAD_LDS(ws, (char*)&Ws[buf][r0 * 64]);
        }
    };

    stage(0, 0);
    asm volatile("s_waitcnt vmcnt(0)" ::: "memory");
    __builtin_amdgcn_s_barrier();
    int cur = 0;

    for (int kk = 0; kk < NC; kk += 64) {
        if (kk + 64 < NC) stage(cur ^ 1, kk + 64);
        short8 a[4][2], b[4][2];
        #pragma unroll
        for (int mr = 0; mr < 4; ++mr) {
            a[mr][0] = frag_swz128(Xs[cur], 64 * wr + 16 * mr + l15, g, 0);
            a[mr][1] = frag_swz128(Xs[cur], 64 * wr + 16 * mr + l15, g, 1);
        }
        #pragma unroll
        for (int nc = 0; nc < 4; ++nc) {
            b[nc][0] = frag_swz128(Ws[cur], 64 * wc + 16 * nc + l15, g, 0);
            b[nc][1] = frag_swz128(Ws[cur], 64 * wc + 16 * nc + l15, g, 1);
        }
        #pragma unroll
        for (int mr = 0; mr < 4; ++mr)
            #pragma unroll
            for (int nc = 0; nc < 4; ++nc) {
                acc[mr][nc] = mfma16(a[mr][0], b[nc][0], acc[mr][nc]);
                acc[mr][nc] = mfma16(a[mr][1], b[nc][1], acc[mr][nc]);
            }
        asm volatile("s_waitcnt vmcnt(0)" ::: "memory");
        __builtin_amdgcn_s_barrier();
        cur ^= 1;
    }

    if (which < 2) {
        unsigned short* dst = qk_dst + (size_t)which * (NB * NH * NT * ND);
        #pragma unroll
        for (int mr = 0; mr < 4; ++mr) {
            #pragma unroll
            for (int nc = 0; nc < 4; ++nc) {
                const int n = n0 + 64 * wc + 16 * nc + l15;
                const int hh = n >> 6;
                const int dd = 32 * (nc >> 1) + 8 * (l15 >> 2) + 4 * (nc & 1) + (l15 & 3);
                #pragma unroll
                for (int r = 0; r < 4; ++r) {
                    const int m = m0 + 64 * wr + 16 * mr + 4 * g + r;
                    const int bb = m >> 11, tt = m & (NT - 1);
                    dst[(((size_t)bb * NH + hh) * NT + tt) * ND + dd] = f2bf(acc[mr][nc][r]);
                }
            }
        }
    } else {
        // V: direct transposed write; within-64 logical l = 16mr+4g+r sits at
        // position 32*(mr>>1)+8g+4*(mr&1)+r (contiguous in r).
        #pragma unroll
        for (int mr = 0; mr < 4; ++mr) {
            const int m = m0 + 64 * wr + 16 * mr + 4 * g;   // r = 0 base
            const int bb = m >> 11, tt = m & (NT - 1);
            const int tbase = (tt & ~63) + 32 * (mr >> 1) + 8 * g + 4 * (mr & 1);
            #pragma unroll
            for (int nc = 0; nc < 4; ++nc) {
                const int n = n0 + 64 * wc + 16 * nc + l15;
                const int hh = n >> 6, dd = n & 63;
                ushort4_t o;
                #pragma unroll
                for (int r = 0; r < 4; ++r) o[r] = f2bf(acc[mr][nc][r]);
                *(ushort4_t*)&Vt[(((size_t)bb * NH + hh) * ND + dd) * NT + tbase] = o;
            }
        }
    }
}

// ---------------------------------------------------------------------------
// Pass A (paired dual-strip, q-PARITY split, NBUF=3 counted pipeline, XCD):
// block (bh, j, p) sums exp2 over q-tiles qt ≡ p (mod 2); writes RAW partial
// sums to Lc2[p]; log2 deferred to attn_pv's Ls staging.
// ---------------------------------------------------------------------------
__global__ __launch_bounds__(256, 4) void colstats(const unsigned short* __restrict__ Qh,
                                                   const unsigned short* __restrict__ Kh,
                                                   float* __restrict__ Lc2) {
    __shared__ __align__(16) unsigned short Qs[3][4096];
    const int tid = threadIdx.x;
    const int lane = tid & 63, w = tid >> 6;
    const int g = lane >> 4, l15 = lane & 15;
    const int subrow = lane >> 3;
    const int src_off = (((lane & 7) ^ subrow) << 4);
    const int lin = blockIdx.x + 32 * blockIdx.y;       // 0..1023
    const int xcd = lin & 7, idx = lin >> 3;            // idx 0..127
    const int bh = xcd * 4 + (idx & 3);
    const int rest = idx >> 2;                          // 0..31
    const int j = rest >> 1, par = rest & 1;
    const int jA = j, jB = 31 - j;
    const int hh = bh & (NH - 1);
    const float slL2 = exp2f(-0.5f * (float)(hh + 1)) * L2E;
    const float C1 = 0.125f * L2E;
    const float s16 = 16.f * slL2;

    const int K0A = 64 * jA, K0B = 64 * jB;
    const unsigned short* krA = Kh + ((size_t)bh * NT + K0A + 16 * w + l15) * ND;
    const unsigned short* krB = Kh + ((size_t)bh * NT + K0B + 16 * w + l15) * ND;
    const short8 akA0 = frag_g(krA, g, 0), akA1 = frag_g(krA, g, 1);
    const short8 akB0 = frag_g(krB, g, 0), akB1 = frag_g(krB, g, 1);
    const int kA0 = K0A + 16 * w + 4 * g;
    const int kB0 = K0B + 16 * w + 4 * g;

    const char* Qbase = (const char*)(Qh + (size_t)bh * NT * ND);
    auto stage = [&](int buf, int q0) {
        const char* qs = Qbase + (size_t)(q0 + 16 * w + subrow) * 128 + src_off;
        char* qd = (char*)&Qs[buf][16 * w * 64];
        GLOAD_LDS(qs, qd);
        GLOAD_LDS(qs + 1024, qd + 1024);
    };

    f32x4 accA = {}, accB = {};
    float rs[4];
    #pragma unroll
    for (int r = 0; r < 4; ++r) rs[r] = (float)r * slL2;

    const int qt0 = jA + ((par ^ jA) & 1);              // first qt >= jA with qt%2 == par
    stage(0, 64 * qt0);
    stage(1, 64 * (qt0 + 2));
    int cur = 0, nxt = 2;

    auto strip = [&](const short8* qf, const short8& a0, const short8& a1,
                     f32x4& acc, float b0, bool mask) {
        #pragma unroll
        for (int q4 = 0; q4 < 4; ++q4) {
            f32x4 d = {};
            __builtin_amdgcn_s_setprio(1);
            d = mfma16(a0, qf[2 * q4], d);
            d = mfma16(a1, qf[2 * q4 + 1], d);
            __builtin_amdgcn_s_setprio(0);
            #pragma unroll
            for (int r = 0; r < 4; ++r) {
                float e = exp2f(fmaf(d[r], C1, b0 + rs[r]));
                if (mask && (16 * q4 + l15 < 16 * w + 4 * g + r)) e = 0.f;
                acc[r] += e;
            }
            b0 -= s16;
        }
    };

    for (int qt = qt0; qt < 32; qt += 2) {
        if (qt + 2 < 32) asm volatile("s_waitcnt vmcnt(2)" ::: "memory");
        else             asm volatile("s_waitcnt vmcnt(0)" ::: "memory");
        __builtin_amdgcn_s_barrier();
        if (qt + 4 < 32) stage(nxt, 64 * (qt + 4));
        const unsigned short* tile = Qs[cur];
        short8 qf[8];
        #pragma unroll
        for (int q4 = 0; q4 < 4; ++q4) {
            qf[2 * q4]     = frag_swz128(tile, 16 * q4 + l15, g, 0);
            qf[2 * q4 + 1] = frag_swz128(tile, 16 * q4 + l15, g, 1);
        }
        const int q0 = 64 * qt;
        strip(qf, akA0, akA1, accA, (float)(kA0 - q0 - l15) * slL2, qt == jA);
        if (qt >= jB)
            strip(qf, akB0, akB1, accB, (float)(kB0 - q0 - l15) * slL2, qt == jB);
        cur = (cur == 2) ? 0 : cur + 1;
        nxt = (nxt == 2) ? 0 : nxt + 1;
    }
    #pragma unroll
    for (int off = 1; off <= 8; off <<= 1) {
        #pragma unroll
        for (int r = 0; r < 4; ++r) {
            accA[r] += __shfl_xor(accA[r], off);
            accB[r] += __shfl_xor(accB[r], off);
        }
    }
    if (l15 == 0) {
        float* Lp = Lc2 + (size_t)(par * 32 + bh) * NT;
        #pragma unroll
        for (int r = 0; r < 4; ++r) {
            Lp[kA0 + r] = accA[r];
            Lp[kB0 + r] = accB[r];
        }
    }
}

// ---------------------------------------------------------------------------
// Pass B (paired dual-strip, FULL k-range, NBUF=2 pipeline, XCD swizzle):
// single output buffer (no partial-output duplication). 40KB LDS ->
// 4 blocks/CU. L combined from both colstats halves at Ls staging.
// ---------------------------------------------------------------------------
__global__ __launch_bounds__(256, 4) void attn_pv(const unsigned short* __restrict__ Qh,
                                                  const unsigned short* __restrict__ Kh,
                                                  const unsigned short* __restrict__ Vt,
                                                  const float* __restrict__ Lc2,
                                                  float* __restrict__ att) {
    __shared__ __align__(16) unsigned short Ks[2][4096];
    __shared__ __align__(16) unsigned short Vs[2][4096];
    __shared__ __align__(16) float Ls[NT];
    const int tid = threadIdx.x;
    const int lane = tid & 63, w = tid >> 6;
    const int g = lane >> 4, l15 = lane & 15;
    const int subrow = lane >> 3;
    const int src_off = (((lane & 7) ^ subrow) << 4);
    const int lin = blockIdx.x + 16 * blockIdx.y;       // 0..511
    const int xcd = lin & 7, idx = lin >> 3;            // 0..63
    const int bh = xcd * 4 + (idx & 3);
    const int j = idx >> 2;                             // 0..15
    const int jA = j, jB = 31 - j;
    const int Q0A = 64 * jA, Q0B = 64 * jB;
    const int qA = Q0A + 16 * w + l15;
    const int qB = Q0B + 16 * w + l15;
    const int hh = bh & (NH - 1);
    const int bb = bh >> 4;
    const float slL2 = exp2f(-0.5f * (float)(hh + 1)) * L2E;
    const float C1 = 0.125f * L2E;

    short8 bqA0, bqA1, bqB0, bqB1;
    {
        const unsigned short* qr = Qh + ((size_t)bh * NT + qA) * ND;
        bqA0 = frag_g(qr, g, 0);
        bqA1 = frag_g(qr, g, 1);
        qr = Qh + ((size_t)bh * NT + qB) * ND;
        bqB0 = frag_g(qr, g, 0);
        bqB1 = frag_g(qr, g, 1);
    }

    auto stageKV = [&](int buf, int K0) {
        const char* ksrc = (const char*)Kh + (size_t)((size_t)bh * NT + K0 + 16 * w + subrow) * 128 + src_off;
        char* kdst = (char*)&Ks[buf][16 * w * 64];
        GLOAD_LDS(ksrc, kdst);
        GLOAD_LDS(ksrc + 1024, kdst + 1024);
        const char* vsrc = (const char*)Vt + ((((size_t)bh * ND + 16 * w + subrow) * NT + K0) << 1) + src_off;
        char* vdst = (char*)&Vs[buf][16 * w * 64];
        GLOAD_LDS(vsrc, vdst);
        GLOAD_LDS(vsrc + 8 * NT * 2, vdst + 1024);
    };

    stageKV(0, 0);
    {   // stage L row: combine both colstats halves, fold k*slope
        const f32x4* La = (const f32x4*)(Lc2 + (size_t)bh * NT);
        const f32x4* Lb = (const f32x4*)(Lc2 + (size_t)(32 + bh) * NT);
        const int nv = (jB + 1) * 16;
        for (int i = tid; i < nv; i += 256) {
            f32x4 a = La[i], b = Lb[i];
            float kb = (float)(4 * i);
            f32x4 v;
            #pragma unroll
            for (int c = 0; c < 4; ++c)
                v[c] = log2f(a[c] + b[c]) - (kb + (float)c) * slL2;
            ((f32x4*)Ls)[i] = v;
        }
    }
    asm volatile("s_waitcnt vmcnt(0) lgkmcnt(0)" ::: "memory");
    __builtin_amdgcn_s_barrier();
    int cur = 0;

    f32x4 oA[4] = {}, oB[4] = {};
    const float qsA = (float)qA * slL2;
    const float qsB = (float)qB * slL2;

    auto dostrip = [&](const short8* kf, const short8* vf,
                       const short8& q0f, const short8& q1f, f32x4 (&o)[4],
                       float qsc, int q, int K0, bool mask) {
        f32x4 pacc[4];
        __builtin_amdgcn_s_setprio(1);
        #pragma unroll
        for (int s4 = 0; s4 < 4; ++s4) {
            f32x4 d = {};
            d = mfma16(kf[2 * s4], q0f, d);
            d = mfma16(kf[2 * s4 + 1], q1f, d);
            pacc[s4] = d;
        }
        __builtin_amdgcn_s_setprio(0);
        union { unsigned u[4]; short8 s; } pa[2];
        #pragma unroll
        for (int s4 = 0; s4 < 4; ++s4) {
            f32x4 Lf = *(const f32x4*)&Ls[K0 + 16 * s4 + 4 * g];
            float p[4];
            #pragma unroll
            for (int r = 0; r < 4; ++r)
                p[r] = exp2f(fmaf(pacc[s4][r], C1, -(Lf[r] + qsc)));
            if (mask) {
                #pragma unroll
                for (int r = 0; r < 4; ++r)
                    if (K0 + 16 * s4 + 4 * g + r > q) p[r] = 0.f;
            }
            pa[s4 >> 1].u[2 * (s4 & 1)]     = cvtpk_bf16(p[0], p[1]);
            pa[s4 >> 1].u[2 * (s4 & 1) + 1] = cvtpk_bf16(p[2], p[3]);
        }
        __builtin_amdgcn_s_setprio(1);
        #pragma unroll
        for (int n = 0; n < 4; ++n) {
            o[n] = mfma16(pa[0].s, vf[2 * n], o[n]);
            o[n] = mfma16(pa[1].s, vf[2 * n + 1], o[n]);
        }
        __builtin_amdgcn_s_setprio(0);
    };

    for (int kt = 0; kt <= jB; ++kt) {
        if (kt < jB) stageKV(cur ^ 1, 64 * (kt + 1));
        const int K0 = 64 * kt;
        short8 kf[8], vf[8];
        #pragma unroll
        for (int s4 = 0; s4 < 4; ++s4) {
            kf[2 * s4]     = frag_swz128(Ks[cur], 16 * s4 + l15, g, 0);
            kf[2 * s4 + 1] = frag_swz128(Ks[cur], 16 * s4 + l15, g, 1);
            vf[2 * s4]     = frag_swz128(Vs[cur], 16 * s4 + l15, g, 0);
            vf[2 * s4 + 1] = frag_swz128(Vs[cur], 16 * s4 + l15, g, 1);
        }
        dostrip(kf, vf, bqB0, bqB1, oB, qsB, qB, K0, kt == jB);
        if (kt <= jA)
            dostrip(kf, vf, bqA0, bqA1, oA, qsA, qA, K0, kt == jA);
        asm volatile("s_waitcnt vmcnt(0)" ::: "memory");
        __builtin_amdgcn_s_barrier();
        cur ^= 1;
    }
    // att layout: [b][t][h][d]
    #pragma unroll
    for (int n = 0; n < 4; ++n) {
        #pragma unroll
        for (int r = 0; r < 4; ++r) {
            att[(((size_t)bb * NT + Q0A + 16 * w + 4 * g + r) * NH + hh) * ND + 16 * n + l15] = oA[n][r];
            att[(((size_t)bb * NT + Q0B + 16 * w + 4 * g + r) * NH + hh) * ND + 16 * n + l15] = oB[n][r];
        }
    }
}

// ---------------------------------------------------------------------------
// A[row][d] = bf16( sum_h att[row][h][d] )
// ---------------------------------------------------------------------------
__global__ __launch_bounds__(256) void headsum(const float* __restrict__ att,
                                               unsigned short* __restrict__ A) {
    const int row = blockIdx.x * 16 + (threadIdx.x >> 4);
    const int d0 = (threadIdx.x & 15) * 4;
    const float* p = att + (size_t)row * (NH * ND) + d0;
    f32x4 s = {};
    #pragma unroll
    for (int h = 0; h < NH; ++h)
        s += *(const f32x4*)(p + h * ND);
    ushort4_t o;
    #pragma unroll
    for (int j = 0; j < 4; ++j) o[j] = f2bf(s[j]);
    *(ushort4_t*)&A[(size_t)row * ND + d0] = o;
}

// ---------------------------------------------------------------------------
// out[m,n] = x[m,n] + (A @ wo)[m,n]  via MFMA (logical-order fragments)
// ---------------------------------------------------------------------------
__global__ __launch_bounds__(256) void out_proj(const float* __restrict__ x,
                                                const unsigned short* __restrict__ A,
                                                const unsigned short* __restrict__ Wot,
                                                float* __restrict__ out) {
    const int tid = threadIdx.x;
    const int lane = tid & 63, w = tid >> 6;
    const int g = lane >> 4, l15 = lane & 15;
    const int m0 = blockIdx.x * 64, n0 = blockIdx.y * 64;

    const unsigned short* ar = A + (size_t)(m0 + 16 * w + l15) * ND;
    short8 a0 = frag_load(ar, g, 0);
    short8 a1 = frag_load(ar, g, 1);

    f32x4 acc[4] = {};
    #pragma unroll
    for (int ns = 0; ns < 4; ++ns) {
        const unsigned short* br = Wot + (size_t)(n0 + 16 * ns + l15) * ND;
        acc[ns] = mfma16(a0, frag_load(br, g, 0), acc[ns]);
        acc[ns] = mfma16(a1, frag_load(br, g, 1), acc[ns]);
    }
    #pragma unroll
    for (int ns = 0; ns < 4; ++ns) {
        #pragma unroll
        for (int r = 0; r < 4; ++r) {
            int m = m0 + 16 * w + 4 * g + r;
            int n = n0 + 16 * ns + l15;
            out[(size_t)m * NC + n] = x[(size_t)m * NC + n] + acc[ns][r];
        }
    }
}

// ---------------------------------------------------------------------------
extern "C" void kernel_launch(void* const* d_in, const int* in_sizes, int n_in,
                              void* d_out, int out_size, void* d_ws, size_t ws_size,
                              hipStream_t stream) {
    const float* x  = (const float*)d_in[0];
    const float* wq = (const float*)d_in[1];
    const float* wk = (const float*)d_in[2];
    const float* wv = (const float*)d_in[3];
    const float* wo = (const float*)d_in[4];
    float* out = (float*)d_out;

    const size_t MB = 1u << 20;
    const size_t KB = 1u << 10;
    unsigned char* w8 = (unsigned char*)d_ws;
    unsigned short* Xh  = (unsigned short*)(w8);               //  8 MB (sigma k)
    unsigned short* Wta = (unsigned short*)(w8 + 8 * MB);      //  6 MB [3][n][k-sigma]
    unsigned short* Qh  = (unsigned short*)(w8 + 16 * MB);     //  8 MB (sigma d)
    unsigned short* Kh  = (unsigned short*)(w8 + 24 * MB);     //  8 MB (sigma d)
    unsigned short* Vt  = (unsigned short*)(w8 + 32 * MB);     //  8 MB (sigma t)
    float*          att = (float*)(w8 + 40 * MB);              // 16 MB [b][t][h][d]
    float*          Lc2 = (float*)(w8 + 56 * MB);              // 512 KB (2 halves)
    unsigned short* A   = (unsigned short*)(w8 + 56 * MB + 512 * KB);  // 512 KB
    unsigned short* Wot = (unsigned short*)(w8 + 57 * MB);     // 128 KB

    cvt_x<<<(NB * NT * NC) / 1024, 256, 0, stream>>>(x, Xh, (NB * NT * NC) / 4);
    cvtT3<<<dim3(16, 16, 3), 256, 0, stream>>>(wq, wk, wv, Wta);
    cvtT_wo<<<dim3(1, 16), 256, 0, stream>>>(wo, Wot);

    gemm_qkv<<<dim3(32, 24), 256, 0, stream>>>(Xh, Wta, Qh, Vt);

    colstats<<<dim3(32, 32), 256, 0, stream>>>(Qh, Kh, Lc2);
    attn_pv<<<dim3(16, 32), 256, 0, stream>>>(Qh, Kh, Vt, Lc2, att);

    headsum<<<(NB * NT) / 16, 256, 0, stream>>>(att, A);
    out_proj<<<dim3(64, 16), 256, 0, stream>>>(x, A, Wot, out);
}

// Round 14
// 142.656 us; speedup vs baseline: 1.3273x; 1.3273x over previous
//
#include <hip/hip_runtime.h>
#include <math.h>

#define NB 2
#define NH 16
#define NT 2048
#define ND 64
#define NC 1024
#define L2E 1.44269504f

typedef __attribute__((ext_vector_type(4))) float f32x4;
typedef __attribute__((ext_vector_type(8))) short short8;
typedef __attribute__((ext_vector_type(4))) short short4_t;
typedef __attribute__((ext_vector_type(8))) unsigned short ushort8;
typedef __attribute__((ext_vector_type(4))) unsigned short ushort4_t;

#define GLOAD_LDS(gp, lp)                                                \
    __builtin_amdgcn_global_load_lds(                                    \
        (const __attribute__((address_space(1))) void*)(gp),             \
        (__attribute__((address_space(3))) void*)(lp), 16, 0, 0)

// storage permutation: position p holds logical index
// sigma(p) = 4*((p>>3)&3) + (p&3) + 16*((p>>2)&1) + 32*(p>>5)
// fragment (g,h) = one contiguous 16B at ushort offset 8g+32h.
__device__ __forceinline__ int sigma_p(int p) {
    return 4 * ((p >> 3) & 3) + (p & 3) + 16 * ((p >> 2) & 1) + 32 * (p >> 5);
}

__device__ __forceinline__ unsigned short f2bf(float f) {
    unsigned u = __builtin_bit_cast(unsigned, f);
    unsigned r = (u + 0x7FFFu + ((u >> 16) & 1u)) >> 16;
    return (unsigned short)r;
}

__device__ __forceinline__ unsigned cvtpk_bf16(float lo, float hi) {
    unsigned r;
    asm("v_cvt_pk_bf16_f32 %0, %1, %2" : "=v"(r) : "v"(lo), "v"(hi));
    return r;
}

__device__ __forceinline__ f32x4 mfma16(short8 a, short8 b, f32x4 c) {
    return __builtin_amdgcn_mfma_f32_16x16x32_bf16(a, b, c, 0, 0, 0);
}

// split-fragment load (out_proj path, logical order)
__device__ __forceinline__ short8 frag_load(const unsigned short* rowp, int g, int half) {
    short8 v;
    short4_t lo = *(const short4_t*)(rowp + 4 * g + 32 * half);
    short4_t hi = *(const short4_t*)(rowp + 4 * g + 16 + 32 * half);
    #pragma unroll
    for (int j = 0; j < 4; ++j) { v[j] = lo[j]; v[4 + j] = hi[j]; }
    return v;
}

// sigma-stored global row: fragment = single 16B load
__device__ __forceinline__ short8 frag_g(const unsigned short* rowp, int g, int half) {
    return *(const short8*)(rowp + 8 * g + 32 * half);
}

// sigma-stored LDS tile with per-row chunk XOR swizzle: one ds_read_b128
__device__ __forceinline__ short8 frag_swz128(const unsigned short* tile, int row, int g, int half) {
    const char* p = (const char*)tile + row * 128 + (((g + 4 * half) ^ (row & 7)) << 4);
    return *(const short8*)p;
}

// ---------------------------------------------------------------------------
// x f32 -> bf16 with sigma permutation of each 64-dim block
// ---------------------------------------------------------------------------
__global__ __launch_bounds__(256) void cvt_x(const float* __restrict__ src,
                                             unsigned short* __restrict__ dst, int n4) {
    int i = blockIdx.x * 256 + threadIdx.x;
    if (i >= n4) return;
    const int blk = i >> 4, c4 = i & 15;
    const int gg = (c4 >> 1) & 3, bb = c4 & 1, hh = c4 >> 3;
    f32x4 v = ((const f32x4*)src)[blk * 16 + gg + 4 * bb + 8 * hh];
    ushort4_t o;
    #pragma unroll
    for (int j = 0; j < 4; ++j) o[j] = f2bf(v[j]);
    ((ushort4_t*)dst)[i] = o;
}

// ---------------------------------------------------------------------------
// three weight matrices f32 [k][n] -> bf16 [n][k-sigma], one launch
// ---------------------------------------------------------------------------
__global__ __launch_bounds__(256) void cvtT3(const float* __restrict__ w0,
                                             const float* __restrict__ w1,
                                             const float* __restrict__ w2,
                                             unsigned short* __restrict__ Wt_all) {
    __shared__ __align__(16) float T[64][68];
    const float* W = (blockIdx.z == 0) ? w0 : ((blockIdx.z == 1) ? w1 : w2);
    unsigned short* Wt = Wt_all + (size_t)blockIdx.z * NC * NC;
    const int tid = threadIdx.x;
    const int k0 = blockIdx.x * 64, n0 = blockIdx.y * 64;
    #pragma unroll
    for (int p = 0; p < 4; ++p) {
        int r = 16 * p + (tid >> 4);
        int c = (tid & 15) * 4;
        *(f32x4*)&T[r][c] = *(const f32x4*)&W[(size_t)(k0 + r) * NC + n0 + c];
    }
    __syncthreads();
    const int nr = tid >> 2, kc = (tid & 3) * 16;
    ushort8 o0, o1;
    #pragma unroll
    for (int j = 0; j < 8; ++j) o0[j] = f2bf(T[sigma_p(kc + j)][nr]);
    #pragma unroll
    for (int j = 0; j < 8; ++j) o1[j] = f2bf(T[sigma_p(kc + 8 + j)][nr]);
    unsigned short* q = Wt + (size_t)(n0 + nr) * NC + k0 + kc;
    *(ushort8*)q       = o0;
    *(ushort8*)(q + 8) = o1;
}

// ---------------------------------------------------------------------------
// wo f32 [k=64][n=1024] -> bf16 [n][k] (logical order)
// ---------------------------------------------------------------------------
__global__ __launch_bounds__(256) void cvtT_wo(const float* __restrict__ W,
                                               unsigned short* __restrict__ Wt) {
    __shared__ __align__(16) float T[64][68];
    const int tid = threadIdx.x;
    const int n0 = blockIdx.y * 64;
    #pragma unroll
    for (int p = 0; p < 4; ++p) {
        int r = 16 * p + (tid >> 4);
        int c = (tid & 15) * 4;
        *(f32x4*)&T[r][c] = *(const f32x4*)&W[(size_t)r * NC + n0 + c];
    }
    __syncthreads();
    const int nr = tid >> 2, kc = (tid & 3) * 16;
    ushort8 o0, o1;
    #pragma unroll
    for (int j = 0; j < 8; ++j) { o0[j] = f2bf(T[kc + j][nr]); o1[j] = f2bf(T[kc + 8 + j][nr]); }
    unsigned short* q = Wt + (size_t)(n0 + nr) * ND + kc;
    *(ushort8*)q       = o0;
    *(ushort8*)(q + 8) = o1;
}

// ---------------------------------------------------------------------------
// bf16 MFMA GEMM, 128x128 tile, 4 waves, K-step 64, single launch for Q,K,V.
// Q/K -> sigma-d [bh][t][d']; V -> DIRECT transposed write Vt[bh][d][t-sigma].
// ---------------------------------------------------------------------------
__global__ __launch_bounds__(256) void gemm_qkv(const unsigned short* __restrict__ Xh,
                                                const unsigned short* __restrict__ Wt_all,
                                                unsigned short* __restrict__ qk_dst,
                                                unsigned short* __restrict__ Vt) {
    __shared__ __align__(16) unsigned short Xs[2][8192];
    __shared__ __align__(16) unsigned short Ws[2][8192];
    const int tid = threadIdx.x;
    const int lane = tid & 63, w = tid >> 6;
    const int g = lane >> 4, l15 = lane & 15;
    const int wr = w >> 1, wc = w & 1;
    const int subrow = lane >> 3;
    const int src_off = (((lane & 7) ^ subrow) << 4);
    const int m0 = blockIdx.x * 128;
    const int which = blockIdx.y >> 3;
    const int n0 = (blockIdx.y & 7) * 128;
    const unsigned short* Wt = Wt_all + (size_t)which * NC * NC;

    f32x4 acc[4][4] = {};

    auto stage = [&](int buf, int kk) {
        #pragma unroll
        for (int i = 0; i < 4; ++i) {
            const int r0 = 8 * w + 32 * i;
            const char* xs = (const char*)Xh + (((size_t)(m0 + r0 + subrow) * NC + kk) << 1) + src_off;
            GLOAD_LDS(xs, (char*)&Xs[buf][r0 * 64]);
            const char* ws = (const char*)Wt + (((size_t)(n0 + r0 + subrow) * NC + kk) << 1) + src_off;
            GLOAD_LDS(ws, (char*)&Ws[buf][r0 * 64]);
        }
    };

    stage(0, 0);
    asm volatile("s_waitcnt vmcnt(0)" ::: "memory");
    __builtin_amdgcn_s_barrier();
    int cur = 0;

    for (int kk = 0; kk < NC; kk += 64) {
        if (kk + 64 < NC) stage(cur ^ 1, kk + 64);
        short8 a[4][2], b[4][2];
        #pragma unroll
        for (int mr = 0; mr < 4; ++mr) {
            a[mr][0] = frag_swz128(Xs[cur], 64 * wr + 16 * mr + l15, g, 0);
            a[mr][1] = frag_swz128(Xs[cur], 64 * wr + 16 * mr + l15, g, 1);
        }
        #pragma unroll
        for (int nc = 0; nc < 4; ++nc) {
            b[nc][0] = frag_swz128(Ws[cur], 64 * wc + 16 * nc + l15, g, 0);
            b[nc][1] = frag_swz128(Ws[cur], 64 * wc + 16 * nc + l15, g, 1);
        }
        #pragma unroll
        for (int mr = 0; mr < 4; ++mr)
            #pragma unroll
            for (int nc = 0; nc < 4; ++nc) {
                acc[mr][nc] = mfma16(a[mr][0], b[nc][0], acc[mr][nc]);
                acc[mr][nc] = mfma16(a[mr][1], b[nc][1], acc[mr][nc]);
            }
        asm volatile("s_waitcnt vmcnt(0)" ::: "memory");
        __builtin_amdgcn_s_barrier();
        cur ^= 1;
    }

    if (which < 2) {
        unsigned short* dst = qk_dst + (size_t)which * (NB * NH * NT * ND);
        #pragma unroll
        for (int mr = 0; mr < 4; ++mr) {
            #pragma unroll
            for (int nc = 0; nc < 4; ++nc) {
                const int n = n0 + 64 * wc + 16 * nc + l15;
                const int hh = n >> 6;
                const int dd = 32 * (nc >> 1) + 8 * (l15 >> 2) + 4 * (nc & 1) + (l15 & 3);
                #pragma unroll
                for (int r = 0; r < 4; ++r) {
                    const int m = m0 + 64 * wr + 16 * mr + 4 * g + r;
                    const int bb = m >> 11, tt = m & (NT - 1);
                    dst[(((size_t)bb * NH + hh) * NT + tt) * ND + dd] = f2bf(acc[mr][nc][r]);
                }
            }
        }
    } else {
        // V: direct transposed write; within-64 logical l = 16mr+4g+r sits at
        // position 32*(mr>>1)+8g+4*(mr&1)+r (contiguous in r).
        #pragma unroll
        for (int mr = 0; mr < 4; ++mr) {
            const int m = m0 + 64 * wr + 16 * mr + 4 * g;   // r = 0 base
            const int bb = m >> 11, tt = m & (NT - 1);
            const int tbase = (tt & ~63) + 32 * (mr >> 1) + 8 * g + 4 * (mr & 1);
            #pragma unroll
            for (int nc = 0; nc < 4; ++nc) {
                const int n = n0 + 64 * wc + 16 * nc + l15;
                const int hh = n >> 6, dd = n & 63;
                ushort4_t o;
                #pragma unroll
                for (int r = 0; r < 4; ++r) o[r] = f2bf(acc[mr][nc][r]);
                *(ushort4_t*)&Vt[(((size_t)bb * NH + hh) * ND + dd) * NT + tbase] = o;
            }
        }
    }
}

// ---------------------------------------------------------------------------
// Pass A (paired dual-strip, q-PARITY split, NBUF=3 counted pipeline, XCD):
// block (bh, j, p) sums exp2 over q-tiles qt ≡ p (mod 2); writes RAW partial
// sums to Lc2[p]; log2 deferred to attn_pv's Ls staging.
// ---------------------------------------------------------------------------
__global__ __launch_bounds__(256, 4) void colstats(const unsigned short* __restrict__ Qh,
                                                   const unsigned short* __restrict__ Kh,
                                                   float* __restrict__ Lc2) {
    __shared__ __align__(16) unsigned short Qs[3][4096];
    const int tid = threadIdx.x;
    const int lane = tid & 63, w = tid >> 6;
    const int g = lane >> 4, l15 = lane & 15;
    const int subrow = lane >> 3;
    const int src_off = (((lane & 7) ^ subrow) << 4);
    const int lin = blockIdx.x + 32 * blockIdx.y;       // 0..1023
    const int xcd = lin & 7, idx = lin >> 3;            // idx 0..127
    const int bh = xcd * 4 + (idx & 3);
    const int rest = idx >> 2;                          // 0..31
    const int j = rest >> 1, par = rest & 1;
    const int jA = j, jB = 31 - j;
    const int hh = bh & (NH - 1);
    const float slL2 = exp2f(-0.5f * (float)(hh + 1)) * L2E;
    const float C1 = 0.125f * L2E;
    const float s16 = 16.f * slL2;

    const int K0A = 64 * jA, K0B = 64 * jB;
    const unsigned short* krA = Kh + ((size_t)bh * NT + K0A + 16 * w + l15) * ND;
    const unsigned short* krB = Kh + ((size_t)bh * NT + K0B + 16 * w + l15) * ND;
    const short8 akA0 = frag_g(krA, g, 0), akA1 = frag_g(krA, g, 1);
    const short8 akB0 = frag_g(krB, g, 0), akB1 = frag_g(krB, g, 1);
    const int kA0 = K0A + 16 * w + 4 * g;
    const int kB0 = K0B + 16 * w + 4 * g;

    const char* Qbase = (const char*)(Qh + (size_t)bh * NT * ND);
    auto stage = [&](int buf, int q0) {
        const char* qs = Qbase + (size_t)(q0 + 16 * w + subrow) * 128 + src_off;
        char* qd = (char*)&Qs[buf][16 * w * 64];
        GLOAD_LDS(qs, qd);
        GLOAD_LDS(qs + 1024, qd + 1024);
    };

    f32x4 accA = {}, accB = {};
    float rs[4];
    #pragma unroll
    for (int r = 0; r < 4; ++r) rs[r] = (float)r * slL2;

    const int qt0 = jA + ((par ^ jA) & 1);              // first qt >= jA with qt%2 == par
    stage(0, 64 * qt0);
    stage(1, 64 * (qt0 + 2));
    int cur = 0, nxt = 2;

    auto strip = [&](const short8* qf, const short8& a0, const short8& a1,
                     f32x4& acc, float b0, bool mask) {
        #pragma unroll
        for (int q4 = 0; q4 < 4; ++q4) {
            f32x4 d = {};
            __builtin_amdgcn_s_setprio(1);
            d = mfma16(a0, qf[2 * q4], d);
            d = mfma16(a1, qf[2 * q4 + 1], d);
            __builtin_amdgcn_s_setprio(0);
            #pragma unroll
            for (int r = 0; r < 4; ++r) {
                float e = exp2f(fmaf(d[r], C1, b0 + rs[r]));
                if (mask && (16 * q4 + l15 < 16 * w + 4 * g + r)) e = 0.f;
                acc[r] += e;
            }
            b0 -= s16;
        }
    };

    for (int qt = qt0; qt < 32; qt += 2) {
        if (qt + 2 < 32) asm volatile("s_waitcnt vmcnt(2)" ::: "memory");
        else             asm volatile("s_waitcnt vmcnt(0)" ::: "memory");
        __builtin_amdgcn_s_barrier();
        if (qt + 4 < 32) stage(nxt, 64 * (qt + 4));
        const unsigned short* tile = Qs[cur];
        short8 qf[8];
        #pragma unroll
        for (int q4 = 0; q4 < 4; ++q4) {
            qf[2 * q4]     = frag_swz128(tile, 16 * q4 + l15, g, 0);
            qf[2 * q4 + 1] = frag_swz128(tile, 16 * q4 + l15, g, 1);
        }
        const int q0 = 64 * qt;
        strip(qf, akA0, akA1, accA, (float)(kA0 - q0 - l15) * slL2, qt == jA);
        if (qt >= jB)
            strip(qf, akB0, akB1, accB, (float)(kB0 - q0 - l15) * slL2, qt == jB);
        cur = (cur == 2) ? 0 : cur + 1;
        nxt = (nxt == 2) ? 0 : nxt + 1;
    }
    #pragma unroll
    for (int off = 1; off <= 8; off <<= 1) {
        #pragma unroll
        for (int r = 0; r < 4; ++r) {
            accA[r] += __shfl_xor(accA[r], off);
            accB[r] += __shfl_xor(accB[r], off);
        }
    }
    if (l15 == 0) {
        float* Lp = Lc2 + (size_t)(par * 32 + bh) * NT;
        #pragma unroll
        for (int r = 0; r < 4; ++r) {
            Lp[kA0 + r] = accA[r];
            Lp[kB0 + r] = accB[r];
        }
    }
}

// ---------------------------------------------------------------------------
// Pass B (paired dual-strip, FULL k-range, NBUF=3 COUNTED-vmcnt pipeline,
// XCD swizzle) — the round-10-proven structure. vmcnt(4) in steady state;
// stage(kt+2) issued after the barrier; single full output buffer.
// L combined from the two colstats halves at Ls staging.
// ---------------------------------------------------------------------------
__global__ __launch_bounds__(256) void attn_pv(const unsigned short* __restrict__ Qh,
                                               const unsigned short* __restrict__ Kh,
                                               const unsigned short* __restrict__ Vt,
                                               const float* __restrict__ Lc2,
                                               float* __restrict__ att) {
    __shared__ __align__(16) unsigned short Ks[3][4096];
    __shared__ __align__(16) unsigned short Vs[3][4096];
    __shared__ __align__(16) float Ls[NT];
    const int tid = threadIdx.x;
    const int lane = tid & 63, w = tid >> 6;
    const int g = lane >> 4, l15 = lane & 15;
    const int subrow = lane >> 3;
    const int src_off = (((lane & 7) ^ subrow) << 4);
    const int lin = blockIdx.x + 16 * blockIdx.y;       // 0..511
    const int xcd = lin & 7, idx = lin >> 3;            // 0..63
    const int bh = xcd * 4 + (idx & 3);
    const int j = idx >> 2;                             // 0..15
    const int jA = j, jB = 31 - j;
    const int Q0A = 64 * jA, Q0B = 64 * jB;
    const int qA = Q0A + 16 * w + l15;
    const int qB = Q0B + 16 * w + l15;
    const int hh = bh & (NH - 1);
    const int bb = bh >> 4;
    const float slL2 = exp2f(-0.5f * (float)(hh + 1)) * L2E;
    const float C1 = 0.125f * L2E;

    short8 bqA0, bqA1, bqB0, bqB1;
    {
        const unsigned short* qr = Qh + ((size_t)bh * NT + qA) * ND;
        bqA0 = frag_g(qr, g, 0);
        bqA1 = frag_g(qr, g, 1);
        qr = Qh + ((size_t)bh * NT + qB) * ND;
        bqB0 = frag_g(qr, g, 0);
        bqB1 = frag_g(qr, g, 1);
    }

    auto stageKV = [&](int buf, int K0) {
        const char* ksrc = (const char*)Kh + (size_t)((size_t)bh * NT + K0 + 16 * w + subrow) * 128 + src_off;
        char* kdst = (char*)&Ks[buf][16 * w * 64];
        GLOAD_LDS(ksrc, kdst);
        GLOAD_LDS(ksrc + 1024, kdst + 1024);
        const char* vsrc = (const char*)Vt + ((((size_t)bh * ND + 16 * w + subrow) * NT + K0) << 1) + src_off;
        char* vdst = (char*)&Vs[buf][16 * w * 64];
        GLOAD_LDS(vsrc, vdst);
        GLOAD_LDS(vsrc + 8 * NT * 2, vdst + 1024);
    };

    // prologue: two tiles in flight (jB >= 16 so tile 1 always exists)
    stageKV(0, 0);
    stageKV(1, 64);
    {   // stage L row: combine both colstats halves, fold k*slope
        const f32x4* La = (const f32x4*)(Lc2 + (size_t)bh * NT);
        const f32x4* Lb = (const f32x4*)(Lc2 + (size_t)(32 + bh) * NT);
        const int nv = (jB + 1) * 16;
        for (int i = tid; i < nv; i += 256) {
            f32x4 a = La[i], b = Lb[i];
            float kb = (float)(4 * i);
            f32x4 v;
            #pragma unroll
            for (int c = 0; c < 4; ++c)
                v[c] = log2f(a[c] + b[c]) - (kb + (float)c) * slL2;
            ((f32x4*)Ls)[i] = v;
        }
    }
    asm volatile("s_waitcnt lgkmcnt(0)" ::: "memory");
    int cur = 0, nxt = 2;

    f32x4 oA[4] = {}, oB[4] = {};
    const float qsA = (float)qA * slL2;
    const float qsB = (float)qB * slL2;

    auto dostrip = [&](const short8* kf, const short8* vf,
                       const short8& q0f, const short8& q1f, f32x4 (&o)[4],
                       float qsc, int q, int K0, bool mask) {
        f32x4 pacc[4];
        __builtin_amdgcn_s_setprio(1);
        #pragma unroll
        for (int s4 = 0; s4 < 4; ++s4) {
            f32x4 d = {};
            d = mfma16(kf[2 * s4], q0f, d);
            d = mfma16(kf[2 * s4 + 1], q1f, d);
            pacc[s4] = d;
        }
        __builtin_amdgcn_s_setprio(0);
        union { unsigned u[4]; short8 s; } pa[2];
        #pragma unroll
        for (int s4 = 0; s4 < 4; ++s4) {
            f32x4 Lf = *(const f32x4*)&Ls[K0 + 16 * s4 + 4 * g];
            float p[4];
            #pragma unroll
            for (int r = 0; r < 4; ++r)
                p[r] = exp2f(fmaf(pacc[s4][r], C1, -(Lf[r] + qsc)));
            if (mask) {
                #pragma unroll
                for (int r = 0; r < 4; ++r)
                    if (K0 + 16 * s4 + 4 * g + r > q) p[r] = 0.f;
            }
            pa[s4 >> 1].u[2 * (s4 & 1)]     = cvtpk_bf16(p[0], p[1]);
            pa[s4 >> 1].u[2 * (s4 & 1) + 1] = cvtpk_bf16(p[2], p[3]);
        }
        __builtin_amdgcn_s_setprio(1);
        #pragma unroll
        for (int n = 0; n < 4; ++n) {
            o[n] = mfma16(pa[0].s, vf[2 * n], o[n]);
            o[n] = mfma16(pa[1].s, vf[2 * n + 1], o[n]);
        }
        __builtin_amdgcn_s_setprio(0);
    };

    for (int kt = 0; kt <= jB; ++kt) {
        if (kt < jB) asm volatile("s_waitcnt vmcnt(4)" ::: "memory");
        else         asm volatile("s_waitcnt vmcnt(0)" ::: "memory");
        __builtin_amdgcn_s_barrier();
        if (kt + 2 <= jB) stageKV(nxt, 64 * (kt + 2));
        const int K0 = 64 * kt;
        // hoisted shared-tile fragments (used by both strips)
        short8 kf[8], vf[8];
        #pragma unroll
        for (int s4 = 0; s4 < 4; ++s4) {
            kf[2 * s4]     = frag_swz128(Ks[cur], 16 * s4 + l15, g, 0);
            kf[2 * s4 + 1] = frag_swz128(Ks[cur], 16 * s4 + l15, g, 1);
            vf[2 * s4]     = frag_swz128(Vs[cur], 16 * s4 + l15, g, 0);
            vf[2 * s4 + 1] = frag_swz128(Vs[cur], 16 * s4 + l15, g, 1);
        }
        dostrip(kf, vf, bqB0, bqB1, oB, qsB, qB, K0, kt == jB);
        if (kt <= jA)
            dostrip(kf, vf, bqA0, bqA1, oA, qsA, qA, K0, kt == jA);
        cur = (cur == 2) ? 0 : cur + 1;
        nxt = (nxt == 2) ? 0 : nxt + 1;
    }
    // att layout: [b][t][h][d]
    #pragma unroll
    for (int n = 0; n < 4; ++n) {
        #pragma unroll
        for (int r = 0; r < 4; ++r) {
            att[(((size_t)bb * NT + Q0A + 16 * w + 4 * g + r) * NH + hh) * ND + 16 * n + l15] = oA[n][r];
            att[(((size_t)bb * NT + Q0B + 16 * w + 4 * g + r) * NH + hh) * ND + 16 * n + l15] = oB[n][r];
        }
    }
}

// ---------------------------------------------------------------------------
// A[row][d] = bf16( sum_h att[row][h][d] )
// ---------------------------------------------------------------------------
__global__ __launch_bounds__(256) void headsum(const float* __restrict__ att,
                                               unsigned short* __restrict__ A) {
    const int row = blockIdx.x * 16 + (threadIdx.x >> 4);
    const int d0 = (threadIdx.x & 15) * 4;
    const float* p = att + (size_t)row * (NH * ND) + d0;
    f32x4 s = {};
    #pragma unroll
    for (int h = 0; h < NH; ++h)
        s += *(const f32x4*)(p + h * ND);
    ushort4_t o;
    #pragma unroll
    for (int j = 0; j < 4; ++j) o[j] = f2bf(s[j]);
    *(ushort4_t*)&A[(size_t)row * ND + d0] = o;
}

// ---------------------------------------------------------------------------
// out[m,n] = x[m,n] + (A @ wo)[m,n]  via MFMA (logical-order fragments)
// ---------------------------------------------------------------------------
__global__ __launch_bounds__(256) void out_proj(const float* __restrict__ x,
                                                const unsigned short* __restrict__ A,
                                                const unsigned short* __restrict__ Wot,
                                                float* __restrict__ out) {
    const int tid = threadIdx.x;
    const int lane = tid & 63, w = tid >> 6;
    const int g = lane >> 4, l15 = lane & 15;
    const int m0 = blockIdx.x * 64, n0 = blockIdx.y * 64;

    const unsigned short* ar = A + (size_t)(m0 + 16 * w + l15) * ND;
    short8 a0 = frag_load(ar, g, 0);
    short8 a1 = frag_load(ar, g, 1);

    f32x4 acc[4] = {};
    #pragma unroll
    for (int ns = 0; ns < 4; ++ns) {
        const unsigned short* br = Wot + (size_t)(n0 + 16 * ns + l15) * ND;
        acc[ns] = mfma16(a0, frag_load(br, g, 0), acc[ns]);
        acc[ns] = mfma16(a1, frag_load(br, g, 1), acc[ns]);
    }
    #pragma unroll
    for (int ns = 0; ns < 4; ++ns) {
        #pragma unroll
        for (int r = 0; r < 4; ++r) {
            int m = m0 + 16 * w + 4 * g + r;
            int n = n0 + 16 * ns + l15;
            out[(size_t)m * NC + n] = x[(size_t)m * NC + n] + acc[ns][r];
        }
    }
}

// ---------------------------------------------------------------------------
extern "C" void kernel_launch(void* const* d_in, const int* in_sizes, int n_in,
                              void* d_out, int out_size, void* d_ws, size_t ws_size,
                              hipStream_t stream) {
    const float* x  = (const float*)d_in[0];
    const float* wq = (const float*)d_in[1];
    const float* wk = (const float*)d_in[2];
    const float* wv = (const float*)d_in[3];
    const float* wo = (const float*)d_in[4];
    float* out = (float*)d_out;

    const size_t MB = 1u << 20;
    const size_t KB = 1u << 10;
    unsigned char* w8 = (unsigned char*)d_ws;
    unsigned short* Xh  = (unsigned short*)(w8);               //  8 MB (sigma k)
    unsigned short* Wta = (unsigned short*)(w8 + 8 * MB);      //  6 MB [3][n][k-sigma]
    unsigned short* Qh  = (unsigned short*)(w8 + 16 * MB);     //  8 MB (sigma d)
    unsigned short* Kh  = (unsigned short*)(w8 + 24 * MB);     //  8 MB (sigma d)
    unsigned short* Vt  = (unsigned short*)(w8 + 32 * MB);     //  8 MB (sigma t)
    float*          att = (float*)(w8 + 40 * MB);              // 16 MB [b][t][h][d]
    float*          Lc2 = (float*)(w8 + 56 * MB);              // 512 KB (2 halves)
    unsigned short* A   = (unsigned short*)(w8 + 56 * MB + 512 * KB);  // 512 KB
    unsigned short* Wot = (unsigned short*)(w8 + 57 * MB);     // 128 KB

    cvt_x<<<(NB * NT * NC) / 1024, 256, 0, stream>>>(x, Xh, (NB * NT * NC) / 4);
    cvtT3<<<dim3(16, 16, 3), 256, 0, stream>>>(wq, wk, wv, Wta);
    cvtT_wo<<<dim3(1, 16), 256, 0, stream>>>(wo, Wot);

    gemm_qkv<<<dim3(32, 24), 256, 0, stream>>>(Xh, Wta, Qh, Vt);

    colstats<<<dim3(32, 32), 256, 0, stream>>>(Qh, Kh, Lc2);
    attn_pv<<<dim3(16, 32), 256, 0, stream>>>(Qh, Kh, Vt, Lc2, att);

    headsum<<<(NB * NT) / 16, 256, 0, stream>>>(att, A);
    out_proj<<<dim3(64, 16), 256, 0, stream>>>(x, A, Wot, out);
}

// Round 15
// 141.093 us; speedup vs baseline: 1.3420x; 1.0111x over previous
//
#include <hip/hip_runtime.h>
#include <math.h>

#define NB 2
#define NH 16
#define NT 2048
#define ND 64
#define NC 1024
#define L2E 1.44269504f

typedef __attribute__((ext_vector_type(4))) float f32x4;
typedef __attribute__((ext_vector_type(8))) short short8;
typedef __attribute__((ext_vector_type(4))) short short4_t;
typedef __attribute__((ext_vector_type(8))) unsigned short ushort8;
typedef __attribute__((ext_vector_type(4))) unsigned short ushort4_t;

#define GLOAD_LDS(gp, lp)                                                \
    __builtin_amdgcn_global_load_lds(                                    \
        (const __attribute__((address_space(1))) void*)(gp),             \
        (__attribute__((address_space(3))) void*)(lp), 16, 0, 0)

// storage permutation: position p holds logical index
// sigma(p) = 4*((p>>3)&3) + (p&3) + 16*((p>>2)&1) + 32*(p>>5)
// fragment (g,h) = one contiguous 16B at ushort offset 8g+32h.
__device__ __forceinline__ int sigma_p(int p) {
    return 4 * ((p >> 3) & 3) + (p & 3) + 16 * ((p >> 2) & 1) + 32 * (p >> 5);
}

__device__ __forceinline__ unsigned short f2bf(float f) {
    unsigned u = __builtin_bit_cast(unsigned, f);
    unsigned r = (u + 0x7FFFu + ((u >> 16) & 1u)) >> 16;
    return (unsigned short)r;
}

__device__ __forceinline__ unsigned cvtpk_bf16(float lo, float hi) {
    unsigned r;
    asm("v_cvt_pk_bf16_f32 %0, %1, %2" : "=v"(r) : "v"(lo), "v"(hi));
    return r;
}

__device__ __forceinline__ f32x4 mfma16(short8 a, short8 b, f32x4 c) {
    return __builtin_amdgcn_mfma_f32_16x16x32_bf16(a, b, c, 0, 0, 0);
}

// split-fragment load (out_proj path, logical order)
__device__ __forceinline__ short8 frag_load(const unsigned short* rowp, int g, int half) {
    short8 v;
    short4_t lo = *(const short4_t*)(rowp + 4 * g + 32 * half);
    short4_t hi = *(const short4_t*)(rowp + 4 * g + 16 + 32 * half);
    #pragma unroll
    for (int j = 0; j < 4; ++j) { v[j] = lo[j]; v[4 + j] = hi[j]; }
    return v;
}

// sigma-stored global row: fragment = single 16B load
__device__ __forceinline__ short8 frag_g(const unsigned short* rowp, int g, int half) {
    return *(const short8*)(rowp + 8 * g + 32 * half);
}

// sigma-stored LDS tile with per-row chunk XOR swizzle: one ds_read_b128
__device__ __forceinline__ short8 frag_swz128(const unsigned short* tile, int row, int g, int half) {
    const char* p = (const char*)tile + row * 128 + (((g + 4 * half) ^ (row & 7)) << 4);
    return *(const short8*)p;
}

// ---------------------------------------------------------------------------
// x f32 -> bf16 with sigma permutation of each 64-dim block
// ---------------------------------------------------------------------------
__global__ __launch_bounds__(256) void cvt_x(const float* __restrict__ src,
                                             unsigned short* __restrict__ dst, int n4) {
    int i = blockIdx.x * 256 + threadIdx.x;
    if (i >= n4) return;
    const int blk = i >> 4, c4 = i & 15;
    const int gg = (c4 >> 1) & 3, bb = c4 & 1, hh = c4 >> 3;
    f32x4 v = ((const f32x4*)src)[blk * 16 + gg + 4 * bb + 8 * hh];
    ushort4_t o;
    #pragma unroll
    for (int j = 0; j < 4; ++j) o[j] = f2bf(v[j]);
    ((ushort4_t*)dst)[i] = o;
}

// ---------------------------------------------------------------------------
// three weight matrices f32 [k][n] -> bf16 [n][k-sigma], one launch
// ---------------------------------------------------------------------------
__global__ __launch_bounds__(256) void cvtT3(const float* __restrict__ w0,
                                             const float* __restrict__ w1,
                                             const float* __restrict__ w2,
                                             unsigned short* __restrict__ Wt_all) {
    __shared__ __align__(16) float T[64][68];
    const float* W = (blockIdx.z == 0) ? w0 : ((blockIdx.z == 1) ? w1 : w2);
    unsigned short* Wt = Wt_all + (size_t)blockIdx.z * NC * NC;
    const int tid = threadIdx.x;
    const int k0 = blockIdx.x * 64, n0 = blockIdx.y * 64;
    #pragma unroll
    for (int p = 0; p < 4; ++p) {
        int r = 16 * p + (tid >> 4);
        int c = (tid & 15) * 4;
        *(f32x4*)&T[r][c] = *(const f32x4*)&W[(size_t)(k0 + r) * NC + n0 + c];
    }
    __syncthreads();
    const int nr = tid >> 2, kc = (tid & 3) * 16;
    ushort8 o0, o1;
    #pragma unroll
    for (int j = 0; j < 8; ++j) o0[j] = f2bf(T[sigma_p(kc + j)][nr]);
    #pragma unroll
    for (int j = 0; j < 8; ++j) o1[j] = f2bf(T[sigma_p(kc + 8 + j)][nr]);
    unsigned short* q = Wt + (size_t)(n0 + nr) * NC + k0 + kc;
    *(ushort8*)q       = o0;
    *(ushort8*)(q + 8) = o1;
}

// ---------------------------------------------------------------------------
// wo f32 [k=64][n=1024] -> bf16 [n][k] (logical order)
// ---------------------------------------------------------------------------
__global__ __launch_bounds__(256) void cvtT_wo(const float* __restrict__ W,
                                               unsigned short* __restrict__ Wt) {
    __shared__ __align__(16) float T[64][68];
    const int tid = threadIdx.x;
    const int n0 = blockIdx.y * 64;
    #pragma unroll
    for (int p = 0; p < 4; ++p) {
        int r = 16 * p + (tid >> 4);
        int c = (tid & 15) * 4;
        *(f32x4*)&T[r][c] = *(const f32x4*)&W[(size_t)r * NC + n0 + c];
    }
    __syncthreads();
    const int nr = tid >> 2, kc = (tid & 3) * 16;
    ushort8 o0, o1;
    #pragma unroll
    for (int j = 0; j < 8; ++j) { o0[j] = f2bf(T[kc + j][nr]); o1[j] = f2bf(T[kc + 8 + j][nr]); }
    unsigned short* q = Wt + (size_t)(n0 + nr) * ND + kc;
    *(ushort8*)q       = o0;
    *(ushort8*)(q + 8) = o1;
}

// ---------------------------------------------------------------------------
// bf16 MFMA GEMM, 128x128 tile, 4 waves, K-step 64, single launch for Q,K,V.
// Q/K -> sigma-d [bh][t][d']; V -> DIRECT transposed write Vt[bh][d][t-sigma].
// ---------------------------------------------------------------------------
__global__ __launch_bounds__(256) void gemm_qkv(const unsigned short* __restrict__ Xh,
                                                const unsigned short* __restrict__ Wt_all,
                                                unsigned short* __restrict__ qk_dst,
                                                unsigned short* __restrict__ Vt) {
    __shared__ __align__(16) unsigned short Xs[2][8192];
    __shared__ __align__(16) unsigned short Ws[2][8192];
    const int tid = threadIdx.x;
    const int lane = tid & 63, w = tid >> 6;
    const int g = lane >> 4, l15 = lane & 15;
    const int wr = w >> 1, wc = w & 1;
    const int subrow = lane >> 3;
    const int src_off = (((lane & 7) ^ subrow) << 4);
    const int m0 = blockIdx.x * 128;
    const int which = blockIdx.y >> 3;
    const int n0 = (blockIdx.y & 7) * 128;
    const unsigned short* Wt = Wt_all + (size_t)which * NC * NC;

    f32x4 acc[4][4] = {};

    auto stage = [&](int buf, int kk) {
        #pragma unroll
        for (int i = 0; i < 4; ++i) {
            const int r0 = 8 * w + 32 * i;
            const char* xs = (const char*)Xh + (((size_t)(m0 + r0 + subrow) * NC + kk) << 1) + src_off;
            GLOAD_LDS(xs, (char*)&Xs[buf][r0 * 64]);
            const char* ws = (const char*)Wt + (((size_t)(n0 + r0 + subrow) * NC + kk) << 1) + src_off;
            GLOAD_LDS(ws, (char*)&Ws[buf][r0 * 64]);
        }
    };

    stage(0, 0);
    asm volatile("s_waitcnt vmcnt(0)" ::: "memory");
    __builtin_amdgcn_s_barrier();
    int cur = 0;

    for (int kk = 0; kk < NC; kk += 64) {
        if (kk + 64 < NC) stage(cur ^ 1, kk + 64);
        short8 a[4][2], b[4][2];
        #pragma unroll
        for (int mr = 0; mr < 4; ++mr) {
            a[mr][0] = frag_swz128(Xs[cur], 64 * wr + 16 * mr + l15, g, 0);
            a[mr][1] = frag_swz128(Xs[cur], 64 * wr + 16 * mr + l15, g, 1);
        }
        #pragma unroll
        for (int nc = 0; nc < 4; ++nc) {
            b[nc][0] = frag_swz128(Ws[cur], 64 * wc + 16 * nc + l15, g, 0);
            b[nc][1] = frag_swz128(Ws[cur], 64 * wc + 16 * nc + l15, g, 1);
        }
        #pragma unroll
        for (int mr = 0; mr < 4; ++mr)
            #pragma unroll
            for (int nc = 0; nc < 4; ++nc) {
                acc[mr][nc] = mfma16(a[mr][0], b[nc][0], acc[mr][nc]);
                acc[mr][nc] = mfma16(a[mr][1], b[nc][1], acc[mr][nc]);
            }
        asm volatile("s_waitcnt vmcnt(0)" ::: "memory");
        __builtin_amdgcn_s_barrier();
        cur ^= 1;
    }

    if (which < 2) {
        unsigned short* dst = qk_dst + (size_t)which * (NB * NH * NT * ND);
        #pragma unroll
        for (int mr = 0; mr < 4; ++mr) {
            #pragma unroll
            for (int nc = 0; nc < 4; ++nc) {
                const int n = n0 + 64 * wc + 16 * nc + l15;
                const int hh = n >> 6;
                const int dd = 32 * (nc >> 1) + 8 * (l15 >> 2) + 4 * (nc & 1) + (l15 & 3);
                #pragma unroll
                for (int r = 0; r < 4; ++r) {
                    const int m = m0 + 64 * wr + 16 * mr + 4 * g + r;
                    const int bb = m >> 11, tt = m & (NT - 1);
                    dst[(((size_t)bb * NH + hh) * NT + tt) * ND + dd] = f2bf(acc[mr][nc][r]);
                }
            }
        }
    } else {
        // V: direct transposed write; within-64 logical l = 16mr+4g+r sits at
        // position 32*(mr>>1)+8g+4*(mr&1)+r (contiguous in r).
        #pragma unroll
        for (int mr = 0; mr < 4; ++mr) {
            const int m = m0 + 64 * wr + 16 * mr + 4 * g;   // r = 0 base
            const int bb = m >> 11, tt = m & (NT - 1);
            const int tbase = (tt & ~63) + 32 * (mr >> 1) + 8 * g + 4 * (mr & 1);
            #pragma unroll
            for (int nc = 0; nc < 4; ++nc) {
                const int n = n0 + 64 * wc + 16 * nc + l15;
                const int hh = n >> 6, dd = n & 63;
                ushort4_t o;
                #pragma unroll
                for (int r = 0; r < 4; ++r) o[r] = f2bf(acc[mr][nc][r]);
                *(ushort4_t*)&Vt[(((size_t)bb * NH + hh) * ND + dd) * NT + tbase] = o;
            }
        }
    }
}

// ---------------------------------------------------------------------------
// Pass A (paired dual-strip, q-PARITY split, NBUF=3 counted pipeline, XCD):
// block (bh, j, p) sums exp2 over q-tiles qt ≡ p (mod 2); writes RAW partial
// sums to Lc2[p]; log2 deferred to attn_pv's Ls staging.
// ---------------------------------------------------------------------------
__global__ __launch_bounds__(256, 4) void colstats(const unsigned short* __restrict__ Qh,
                                                   const unsigned short* __restrict__ Kh,
                                                   float* __restrict__ Lc2) {
    __shared__ __align__(16) unsigned short Qs[3][4096];
    const int tid = threadIdx.x;
    const int lane = tid & 63, w = tid >> 6;
    const int g = lane >> 4, l15 = lane & 15;
    const int subrow = lane >> 3;
    const int src_off = (((lane & 7) ^ subrow) << 4);
    const int lin = blockIdx.x + 32 * blockIdx.y;       // 0..1023
    const int xcd = lin & 7, idx = lin >> 3;            // idx 0..127
    const int bh = xcd * 4 + (idx & 3);
    const int rest = idx >> 2;                          // 0..31
    const int j = rest >> 1, par = rest & 1;
    const int jA = j, jB = 31 - j;
    const int hh = bh & (NH - 1);
    const float slL2 = exp2f(-0.5f * (float)(hh + 1)) * L2E;
    const float C1 = 0.125f * L2E;
    const float s16 = 16.f * slL2;

    const int K0A = 64 * jA, K0B = 64 * jB;
    const unsigned short* krA = Kh + ((size_t)bh * NT + K0A + 16 * w + l15) * ND;
    const unsigned short* krB = Kh + ((size_t)bh * NT + K0B + 16 * w + l15) * ND;
    const short8 akA0 = frag_g(krA, g, 0), akA1 = frag_g(krA, g, 1);
    const short8 akB0 = frag_g(krB, g, 0), akB1 = frag_g(krB, g, 1);
    const int kA0 = K0A + 16 * w + 4 * g;
    const int kB0 = K0B + 16 * w + 4 * g;

    const char* Qbase = (const char*)(Qh + (size_t)bh * NT * ND);
    auto stage = [&](int buf, int q0) {
        const char* qs = Qbase + (size_t)(q0 + 16 * w + subrow) * 128 + src_off;
        char* qd = (char*)&Qs[buf][16 * w * 64];
        GLOAD_LDS(qs, qd);
        GLOAD_LDS(qs + 1024, qd + 1024);
    };

    f32x4 accA = {}, accB = {};
    float rs[4];
    #pragma unroll
    for (int r = 0; r < 4; ++r) rs[r] = (float)r * slL2;

    const int qt0 = jA + ((par ^ jA) & 1);              // first qt >= jA with qt%2 == par
    stage(0, 64 * qt0);
    stage(1, 64 * (qt0 + 2));
    int cur = 0, nxt = 2;

    auto strip = [&](const short8* qf, const short8& a0, const short8& a1,
                     f32x4& acc, float b0, bool mask) {
        #pragma unroll
        for (int q4 = 0; q4 < 4; ++q4) {
            f32x4 d = {};
            __builtin_amdgcn_s_setprio(1);
            d = mfma16(a0, qf[2 * q4], d);
            d = mfma16(a1, qf[2 * q4 + 1], d);
            __builtin_amdgcn_s_setprio(0);
            #pragma unroll
            for (int r = 0; r < 4; ++r) {
                float e = exp2f(fmaf(d[r], C1, b0 + rs[r]));
                if (mask && (16 * q4 + l15 < 16 * w + 4 * g + r)) e = 0.f;
                acc[r] += e;
            }
            b0 -= s16;
        }
    };

    for (int qt = qt0; qt < 32; qt += 2) {
        if (qt + 2 < 32) asm volatile("s_waitcnt vmcnt(2)" ::: "memory");
        else             asm volatile("s_waitcnt vmcnt(0)" ::: "memory");
        __builtin_amdgcn_s_barrier();
        if (qt + 4 < 32) stage(nxt, 64 * (qt + 4));
        const unsigned short* tile = Qs[cur];
        short8 qf[8];
        #pragma unroll
        for (int q4 = 0; q4 < 4; ++q4) {
            qf[2 * q4]     = frag_swz128(tile, 16 * q4 + l15, g, 0);
            qf[2 * q4 + 1] = frag_swz128(tile, 16 * q4 + l15, g, 1);
        }
        const int q0 = 64 * qt;
        strip(qf, akA0, akA1, accA, (float)(kA0 - q0 - l15) * slL2, qt == jA);
        if (qt >= jB)
            strip(qf, akB0, akB1, accB, (float)(kB0 - q0 - l15) * slL2, qt == jB);
        cur = (cur == 2) ? 0 : cur + 1;
        nxt = (nxt == 2) ? 0 : nxt + 1;
    }
    #pragma unroll
    for (int off = 1; off <= 8; off <<= 1) {
        #pragma unroll
        for (int r = 0; r < 4; ++r) {
            accA[r] += __shfl_xor(accA[r], off);
            accB[r] += __shfl_xor(accB[r], off);
        }
    }
    if (l15 == 0) {
        float* Lp = Lc2 + (size_t)(par * 32 + bh) * NT;
        #pragma unroll
        for (int r = 0; r < 4; ++r) {
            Lp[kA0 + r] = accA[r];
            Lp[kB0 + r] = accB[r];
        }
    }
}

// ---------------------------------------------------------------------------
// Pass B (paired dual-strip, 8-WAVE split, NBUF=3 counted pipeline, XCD):
// 512 threads. Waves 0-3 own strip B's 64 rows, waves 4-7 strip A's.
// Each wave: one dostrip per k-tile (A-waves conditional on kt<=jA).
// Staging: each wave stages 8 rows of K and 8 rows of V (1 gload each);
// steady-state wait vmcnt(2). Single full output buffer.
// ---------------------------------------------------------------------------
__global__ __launch_bounds__(512) void attn_pv(const unsigned short* __restrict__ Qh,
                                               const unsigned short* __restrict__ Kh,
                                               const unsigned short* __restrict__ Vt,
                                               const float* __restrict__ Lc2,
                                               float* __restrict__ att) {
    __shared__ __align__(16) unsigned short Ks[3][4096];
    __shared__ __align__(16) unsigned short Vs[3][4096];
    __shared__ __align__(16) float Ls[NT];
    const int tid = threadIdx.x;
    const int lane = tid & 63, w = tid >> 6;          // w = 0..7
    const int g = lane >> 4, l15 = lane & 15;
    const int subrow = lane >> 3;                     // 0..7
    const int src_off = (((lane & 7) ^ subrow) << 4);
    const int lin = blockIdx.x + 16 * blockIdx.y;     // 0..511
    const int xcd = lin & 7, idx = lin >> 3;          // 0..63
    const int bh = xcd * 4 + (idx & 3);
    const int j = idx >> 2;                           // 0..15
    const int jA = j, jB = 31 - j;
    const int hh = bh & (NH - 1);
    const int bb = bh >> 4;
    const float slL2 = exp2f(-0.5f * (float)(hh + 1)) * L2E;
    const float C1 = 0.125f * L2E;

    // wave -> strip assignment
    const bool isB = (w < 4);
    const int wl = isB ? w : (w - 4);                 // 0..3 within strip
    const int Q0 = isB ? 64 * jB : 64 * jA;
    const int myJ = isB ? jB : jA;
    const int q = Q0 + 16 * wl + l15;

    short8 bq0, bq1;
    {
        const unsigned short* qr = Qh + ((size_t)bh * NT + q) * ND;
        bq0 = frag_g(qr, g, 0);
        bq1 = frag_g(qr, g, 1);
    }

    auto stageKV = [&](int buf, int K0) {
        const char* ksrc = (const char*)Kh + (size_t)((size_t)bh * NT + K0 + 8 * w + subrow) * 128 + src_off;
        GLOAD_LDS(ksrc, (char*)&Ks[buf][8 * w * 64]);
        const char* vsrc = (const char*)Vt + ((((size_t)bh * ND + 8 * w + subrow) * NT + K0) << 1) + src_off;
        GLOAD_LDS(vsrc, (char*)&Vs[buf][8 * w * 64]);
    };

    // prologue: two tiles in flight (jB >= 16 so tile 1 always exists)
    stageKV(0, 0);
    stageKV(1, 64);
    {   // stage L row: combine both colstats halves, fold k*slope
        const f32x4* La = (const f32x4*)(Lc2 + (size_t)bh * NT);
        const f32x4* Lb = (const f32x4*)(Lc2 + (size_t)(32 + bh) * NT);
        const int nv = (jB + 1) * 16;
        for (int i = tid; i < nv; i += 512) {
            f32x4 a = La[i], b = Lb[i];
            float kb = (float)(4 * i);
            f32x4 v;
            #pragma unroll
            for (int c = 0; c < 4; ++c)
                v[c] = log2f(a[c] + b[c]) - (kb + (float)c) * slL2;
            ((f32x4*)Ls)[i] = v;
        }
    }
    asm volatile("s_waitcnt lgkmcnt(0)" ::: "memory");
    int cur = 0, nxt = 2;

    f32x4 o[4] = {};
    const float qsc = (float)q * slL2;

    auto dostrip = [&](const short8* kf, const short8* vf, int K0, bool mask) {
        f32x4 pacc[4];
        __builtin_amdgcn_s_setprio(1);
        #pragma unroll
        for (int s4 = 0; s4 < 4; ++s4) {
            f32x4 d = {};
            d = mfma16(kf[2 * s4], bq0, d);
            d = mfma16(kf[2 * s4 + 1], bq1, d);
            pacc[s4] = d;
        }
        __builtin_amdgcn_s_setprio(0);
        union { unsigned u[4]; short8 s; } pa[2];
        #pragma unroll
        for (int s4 = 0; s4 < 4; ++s4) {
            f32x4 Lf = *(const f32x4*)&Ls[K0 + 16 * s4 + 4 * g];
            float p[4];
            #pragma unroll
            for (int r = 0; r < 4; ++r)
                p[r] = exp2f(fmaf(pacc[s4][r], C1, -(Lf[r] + qsc)));
            if (mask) {
                #pragma unroll
                for (int r = 0; r < 4; ++r)
                    if (K0 + 16 * s4 + 4 * g + r > q) p[r] = 0.f;
            }
            pa[s4 >> 1].u[2 * (s4 & 1)]     = cvtpk_bf16(p[0], p[1]);
            pa[s4 >> 1].u[2 * (s4 & 1) + 1] = cvtpk_bf16(p[2], p[3]);
        }
        __builtin_amdgcn_s_setprio(1);
        #pragma unroll
        for (int n = 0; n < 4; ++n) {
            o[n] = mfma16(pa[0].s, vf[2 * n], o[n]);
            o[n] = mfma16(pa[1].s, vf[2 * n + 1], o[n]);
        }
        __builtin_amdgcn_s_setprio(0);
    };

    for (int kt = 0; kt <= jB; ++kt) {
        if (kt < jB) asm volatile("s_waitcnt vmcnt(2)" ::: "memory");
        else         asm volatile("s_waitcnt vmcnt(0)" ::: "memory");
        __builtin_amdgcn_s_barrier();
        if (kt + 2 <= jB) stageKV(nxt, 64 * (kt + 2));
        if (kt <= myJ) {
            const int K0 = 64 * kt;
            short8 kf[8], vf[8];
            #pragma unroll
            for (int s4 = 0; s4 < 4; ++s4) {
                kf[2 * s4]     = frag_swz128(Ks[cur], 16 * s4 + l15, g, 0);
                kf[2 * s4 + 1] = frag_swz128(Ks[cur], 16 * s4 + l15, g, 1);
                vf[2 * s4]     = frag_swz128(Vs[cur], 16 * s4 + l15, g, 0);
                vf[2 * s4 + 1] = frag_swz128(Vs[cur], 16 * s4 + l15, g, 1);
            }
            dostrip(kf, vf, K0, kt == myJ);
        }
        cur = (cur == 2) ? 0 : cur + 1;
        nxt = (nxt == 2) ? 0 : nxt + 1;
    }
    // att layout: [b][t][h][d]
    #pragma unroll
    for (int n = 0; n < 4; ++n) {
        #pragma unroll
        for (int r = 0; r < 4; ++r) {
            att[(((size_t)bb * NT + Q0 + 16 * wl + 4 * g + r) * NH + hh) * ND + 16 * n + l15] = o[n][r];
        }
    }
}

// ---------------------------------------------------------------------------
// A[row][d] = bf16( sum_h att[row][h][d] )
// ---------------------------------------------------------------------------
__global__ __launch_bounds__(256) void headsum(const float* __restrict__ att,
                                               unsigned short* __restrict__ A) {
    const int row = blockIdx.x * 16 + (threadIdx.x >> 4);
    const int d0 = (threadIdx.x & 15) * 4;
    const float* p = att + (size_t)row * (NH * ND) + d0;
    f32x4 s = {};
    #pragma unroll
    for (int h = 0; h < NH; ++h)
        s += *(const f32x4*)(p + h * ND);
    ushort4_t o;
    #pragma unroll
    for (int j = 0; j < 4; ++j) o[j] = f2bf(s[j]);
    *(ushort4_t*)&A[(size_t)row * ND + d0] = o;
}

// ---------------------------------------------------------------------------
// out[m,n] = x[m,n] + (A @ wo)[m,n]  via MFMA (logical-order fragments)
// ---------------------------------------------------------------------------
__global__ __launch_bounds__(256) void out_proj(const float* __restrict__ x,
                                                const unsigned short* __restrict__ A,
                                                const unsigned short* __restrict__ Wot,
                                                float* __restrict__ out) {
    const int tid = threadIdx.x;
    const int lane = tid & 63, w = tid >> 6;
    const int g = lane >> 4, l15 = lane & 15;
    const int m0 = blockIdx.x * 64, n0 = blockIdx.y * 64;

    const unsigned short* ar = A + (size_t)(m0 + 16 * w + l15) * ND;
    short8 a0 = frag_load(ar, g, 0);
    short8 a1 = frag_load(ar, g, 1);

    f32x4 acc[4] = {};
    #pragma unroll
    for (int ns = 0; ns < 4; ++ns) {
        const unsigned short* br = Wot + (size_t)(n0 + 16 * ns + l15) * ND;
        acc[ns] = mfma16(a0, frag_load(br, g, 0), acc[ns]);
        acc[ns] = mfma16(a1, frag_load(br, g, 1), acc[ns]);
    }
    #pragma unroll
    for (int ns = 0; ns < 4; ++ns) {
        #pragma unroll
        for (int r = 0; r < 4; ++r) {
            int m = m0 + 16 * w + 4 * g + r;
            int n = n0 + 16 * ns + l15;
            out[(size_t)m * NC + n] = x[(size_t)m * NC + n] + acc[ns][r];
        }
    }
}

// ---------------------------------------------------------------------------
extern "C" void kernel_launch(void* const* d_in, const int* in_sizes, int n_in,
                              void* d_out, int out_size, void* d_ws, size_t ws_size,
                              hipStream_t stream) {
    const float* x  = (const float*)d_in[0];
    const float* wq = (const float*)d_in[1];
    const float* wk = (const float*)d_in[2];
    const float* wv = (const float*)d_in[3];
    const float* wo = (const float*)d_in[4];
    float* out = (float*)d_out;

    const size_t MB = 1u << 20;
    const size_t KB = 1u << 10;
    unsigned char* w8 = (unsigned char*)d_ws;
    unsigned short* Xh  = (unsigned short*)(w8);               //  8 MB (sigma k)
    unsigned short* Wta = (unsigned short*)(w8 + 8 * MB);      //  6 MB [3][n][k-sigma]
    unsigned short* Qh  = (unsigned short*)(w8 + 16 * MB);     //  8 MB (sigma d)
    unsigned short* Kh  = (unsigned short*)(w8 + 24 * MB);     //  8 MB (sigma d)
    unsigned short* Vt  = (unsigned short*)(w8 + 32 * MB);     //  8 MB (sigma t)
    float*          att = (float*)(w8 + 40 * MB);              // 16 MB [b][t][h][d]
    float*          Lc2 = (float*)(w8 + 56 * MB);              // 512 KB (2 halves)
    unsigned short* A   = (unsigned short*)(w8 + 56 * MB + 512 * KB);  // 512 KB
    unsigned short* Wot = (unsigned short*)(w8 + 57 * MB);     // 128 KB

    cvt_x<<<(NB * NT * NC) / 1024, 256, 0, stream>>>(x, Xh, (NB * NT * NC) / 4);
    cvtT3<<<dim3(16, 16, 3), 256, 0, stream>>>(wq, wk, wv, Wta);
    cvtT_wo<<<dim3(1, 16), 256, 0, stream>>>(wo, Wot);

    gemm_qkv<<<dim3(32, 24), 256, 0, stream>>>(Xh, Wta, Qh, Vt);

    colstats<<<dim3(32, 32), 256, 0, stream>>>(Qh, Kh, Lc2);
    attn_pv<<<dim3(16, 32), 512, 0, stream>>>(Qh, Kh, Vt, Lc2, att);

    headsum<<<(NB * NT) / 16, 256, 0, stream>>>(att, A);
    out_proj<<<dim3(64, 16), 256, 0, stream>>>(x, A, Wot, out);
}